// Round 4
// baseline (119.906 us; speedup 1.0000x reference)
//
#include <hip/hip_runtime.h>
#include <stdint.h>

#define NROWS 8192
#define DDIM  128
#define NCHUNK 16
#define CPC   512
#define NPHASE 8             // 4 tiles x 2 K-halves
#define NCC   32             // partial columns per row (NCHUNK * 2 col-waves)

#define LN2   0.6931471805599453f
#define SCALE 14.426950408889634f   // 10 * log2(e)
#define DELTA 18.0f                 // skip margin (log2 units)

typedef __bf16 bf16x4 __attribute__((ext_vector_type(4)));
typedef __bf16 bf16x8 __attribute__((ext_vector_type(8)));
typedef float  f32x4  __attribute__((ext_vector_type(4)));

__device__ __forceinline__ void gload_lds16(const void* g, void* l) {
    __builtin_amdgcn_global_load_lds(
        (const __attribute__((address_space(1))) void*)g,
        (__attribute__((address_space(3))) void*)l, 16, 0, 0);
}

// ---------------------------------------------------------------- t -> bf16
__global__ void convert_kernel(const float* __restrict__ t, __bf16* __restrict__ tb) {
    int idx = blockIdx.x * 256 + threadIdx.x;
    float4 v = reinterpret_cast<const float4*>(t)[idx];
    bf16x4 o;
    o[0] = (__bf16)v.x; o[1] = (__bf16)v.y; o[2] = (__bf16)v.z; o[3] = (__bf16)v.w;
    reinterpret_cast<bf16x4*>(tb)[idx] = o;
}

// -------- shared GEMM skeleton: block = 128 rows x 512 cols, 4 waves (2x2),
// wave = 64 rows x 64 cols per 128-col tile; swapped-operand MFMA so each
// lane's acc quad belongs to ONE row. B staged in K-halves (16KB dbuf),
// pre-swizzled source + linear LDS dest + swizzled ds_read (rule #21).
template<int PASS>
__global__ __launch_bounds__(256, 2) void gemm_pass(
    const __bf16* __restrict__ tb,
    const float* __restrict__ Mrow, const float* __restrict__ sv10,
    float* __restrict__ O1, float* __restrict__ O2) {
    __shared__ __bf16 Bt[2][128 * 64];

    const int tid    = threadIdx.x;
    const int stripe = blockIdx.x >> 4;
    const int chunk  = blockIdx.x & 15;
    const int row0   = stripe * 128;
    const int col0   = chunk * CPC;

    const int lane = tid & 63;
    const int wid  = tid >> 6;
    const int wr   = wid >> 1;      // row-wave (0..1): 64 rows
    const int wc   = wid & 1;       // col-wave (0..1): 64 cols of each tile
    const int g    = lane >> 4;
    const int lr   = lane & 15;
    const int swz  = (lr & 7) << 4;
    const int wave_base = (tid & 0xffffffc0) * 16;

    const uint4* src4 = reinterpret_cast<const uint4*>(tb);
    auto STAGE = [&](int p, int buf) {
        const int tile = p >> 1, kh = p & 1;
        const int base = (col0 + tile * 128) * 16 + kh * 8;
        #pragma unroll
        for (int it = 0; it < 4; ++it) {
            int idx = it * 256 + tid;
            int r = idx >> 3, c = idx & 7;
            gload_lds16(src4 + base + r * 16 + (c ^ (r & 7)),
                        reinterpret_cast<char*>(&Bt[buf][0]) + it * 4096 + wave_base);
        }
    };
    STAGE(0, 0);

    // A (row-side) fragments: 64 rows, all K, in registers
    bf16x8 af[4][4];
    #pragma unroll
    for (int nr = 0; nr < 4; ++nr) {
        const __bf16* arow = tb + (size_t)(row0 + wr * 64 + nr * 16 + lr) * DDIM + g * 8;
        #pragma unroll
        for (int kk = 0; kk < 4; ++kk)
            af[nr][kk] = *reinterpret_cast<const bf16x8*>(arow + kk * 32);
    }

    float st_sv[4], st_M[4], rA[4], rB[4];
    #pragma unroll
    for (int nr = 0; nr < 4; ++nr) {
        if (PASS == 2) {
            int row = row0 + wr * 64 + nr * 16 + lr;
            st_sv[nr] = sv10[row];
            st_M[nr]  = Mrow[row];
            rA[nr] = 0.0f;                   // running exp-sum
        } else {
            rA[nr] = 1e30f;  rB[nr] = -1e30f;  // running min / max
        }
    }

    f32x4 acc[4][4];
    for (int p = 0; p < NPHASE; ++p) {
        __syncthreads();
        if (p + 1 < NPHASE) STAGE(p + 1, (p + 1) & 1);

        if (!(p & 1)) {
            #pragma unroll
            for (int nc = 0; nc < 4; ++nc)
                #pragma unroll
                for (int nr = 0; nr < 4; ++nr)
                    acc[nc][nr] = (f32x4){0.f, 0.f, 0.f, 0.f};
        }

        const char* Bb = reinterpret_cast<const char*>(&Bt[p & 1][0]);
        #pragma unroll
        for (int kk2 = 0; kk2 < 2; ++kk2) {
            bf16x8 bfr[4];
            #pragma unroll
            for (int nc = 0; nc < 4; ++nc) {
                int off = (wc * 64 + nc * 16 + lr) * 128 + ((g * 16 + kk2 * 64) ^ swz);
                bfr[nc] = *reinterpret_cast<const bf16x8*>(Bb + off);
            }
            const int kk = (p & 1) * 2 + kk2;
            #pragma unroll
            for (int nc = 0; nc < 4; ++nc)
                #pragma unroll
                for (int nr = 0; nr < 4; ++nr)
                    acc[nc][nr] = __builtin_amdgcn_mfma_f32_16x16x32_bf16(
                        bfr[nc], af[nr][kk], acc[nc][nr], 0, 0, 0);
        }

        if (p & 1) {   // tile complete
            #pragma unroll
            for (int nr = 0; nr < 4; ++nr) {
                if (PASS == 1) {
                    float mn = rA[nr], mx = rB[nr];
                    #pragma unroll
                    for (int nc = 0; nc < 4; ++nc)
                        #pragma unroll
                        for (int j = 0; j < 4; ++j) {
                            float v = acc[nc][nr][j];
                            mn = fminf(mn, v);  mx = fmaxf(mx, v);
                        }
                    rA[nr] = mn;  rB[nr] = mx;
                } else {
                    float mn = acc[0][nr][0], mx = acc[0][nr][0];
                    #pragma unroll
                    for (int nc = 0; nc < 4; ++nc)
                        #pragma unroll
                        for (int j = 0; j < 4; ++j) {
                            float v = acc[nc][nr][j];
                            mn = fminf(mn, v);  mx = fmaxf(mx, v);
                        }
                    float sv = st_sv[nr];
                    float hi = fmaxf(fmaf(mn, -SCALE, sv), fmaf(mx, SCALE, -sv));
                    if (__any(hi > st_M[nr] - DELTA)) {
                        float s = 0.0f;
                        #pragma unroll
                        for (int nc = 0; nc < 4; ++nc)
                            #pragma unroll
                            for (int j = 0; j < 4; ++j)
                                s += exp2f(fabsf(fmaf(acc[nc][nr][j], -SCALE, sv)) - st_M[nr]);
                        rA[nr] += s;
                    }
                }
            }
        }
    }

    const int cc = chunk * 2 + wc;
    #pragma unroll
    for (int nr = 0; nr < 4; ++nr) {
        int row = row0 + wr * 64 + nr * 16 + lr;
        if (PASS == 1) {
            float mn = rA[nr], mx = rB[nr];
            mn = fminf(mn, __shfl_xor(mn, 16));  mn = fminf(mn, __shfl_xor(mn, 32));
            mx = fmaxf(mx, __shfl_xor(mx, 16));  mx = fmaxf(mx, __shfl_xor(mx, 32));
            if (lane < 16) { O1[row * NCC + cc] = mn;  O2[row * NCC + cc] = mx; }
        } else {
            float s = rA[nr];
            s += __shfl_xor(s, 16);  s += __shfl_xor(s, 32);
            if (lane < 16) O1[row * NCC + cc] = s;
        }
    }
}

// ---- per-row: exact dots (fp32) + global min/max scan -> M, sv, num
__global__ void rowdots_kernel(const float* __restrict__ q, const float* __restrict__ t,
                               const int* __restrict__ jidx,
                               const float* __restrict__ Pmin, const float* __restrict__ Pmax,
                               float* __restrict__ Mrow, float* __restrict__ sv10,
                               float* __restrict__ num) {
    int i    = (blockIdx.x * 256 + threadIdx.x) >> 6;
    int lane = threadIdx.x & 63;
    int j = jidx[i];
    float2 qi = reinterpret_cast<const float2*>(q + (size_t)i * DDIM)[lane];
    float2 qj = reinterpret_cast<const float2*>(q + (size_t)j * DDIM)[lane];
    float2 ti = reinterpret_cast<const float2*>(t + (size_t)i * DDIM)[lane];
    float2 tj = reinterpret_cast<const float2*>(t + (size_t)j * DDIM)[lane];
    float dq = fmaf(qi.x, qj.x, qi.y * qj.y);
    float dt = fmaf(ti.x, tj.x, ti.y * tj.y);
    #pragma unroll
    for (int off = 32; off; off >>= 1) {
        dq += __shfl_xor(dq, off);
        dt += __shfl_xor(dt, off);
    }
    float mn = (lane < 32) ? Pmin[i * NCC + lane] :  1e30f;
    float mx = (lane < 32) ? Pmax[i * NCC + lane] : -1e30f;
    #pragma unroll
    for (int off = 16; off; off >>= 1) {
        mn = fminf(mn, __shfl_xor(mn, off));
        mx = fmaxf(mx, __shfl_xor(mx, off));
    }
    if (lane == 0) {
        float sv = SCALE * dq;
        Mrow[i] = fmaxf(fmaf(mn, -SCALE, sv), fmaf(mx, SCALE, -sv));
        sv10[i] = sv;
        num[i]  = 10.0f * fabsf(dq - dt);
    }
}

// ---- final: S per row (plain adds, shared M), loss, atomic accumulate
__global__ void fin_kernel(const float* __restrict__ Psum, const float* __restrict__ Mrow,
                           const float* __restrict__ num, float* __restrict__ out) {
    int tid = threadIdx.x;
    int row = blockIdx.x * 256 + tid;
    const float4* p = reinterpret_cast<const float4*>(Psum + (size_t)row * NCC);
    float S = 0.0f;
    #pragma unroll
    for (int c = 0; c < 8; ++c) {
        float4 v = p[c];
        S += (v.x + v.y) + (v.z + v.w);
    }
    float acc = LN2 * (Mrow[row] + log2f(S)) - num[row];
    __shared__ float red[256];
    red[tid] = acc;
    __syncthreads();
    for (int s2 = 128; s2 > 0; s2 >>= 1) {
        if (tid < s2) red[tid] += red[tid + s2];
        __syncthreads();
    }
    if (tid == 0) atomicAdd(out, red[0] * (1.0f / (float)NROWS));
}

extern "C" void kernel_launch(void* const* d_in, const int* in_sizes, int n_in,
                              void* d_out, int out_size, void* d_ws, size_t ws_size,
                              hipStream_t stream) {
    const float* q   = (const float*)d_in[0];
    const float* t   = (const float*)d_in[1];
    const int* jidx  = (const int*)d_in[3];
    float* out       = (float*)d_out;

    char* ws    = (char*)d_ws;
    __bf16* tb  = (__bf16*)ws;                                   // 2 MB
    float* Pmin = (float*)(ws + (size_t)NROWS * DDIM * 2);       // 1 MB
    float* Pmax = Pmin + (size_t)NROWS * NCC;                    // 1 MB
    float* Psum = Pmax + (size_t)NROWS * NCC;                    // 1 MB
    float* Mr   = Psum + (size_t)NROWS * NCC;
    float* sv   = Mr + NROWS;
    float* num  = sv + NROWS;

    hipLaunchKernelGGL(convert_kernel, dim3(NROWS * DDIM / 4 / 256), dim3(256), 0, stream,
                       t, tb);
    hipLaunchKernelGGL((gemm_pass<1>), dim3(64 * NCHUNK), dim3(256), 0, stream,
                       tb, nullptr, nullptr, Pmin, Pmax);
    hipLaunchKernelGGL(rowdots_kernel, dim3(NROWS / 4), dim3(256), 0, stream,
                       q, t, jidx, Pmin, Pmax, Mr, sv, num);
    hipLaunchKernelGGL((gemm_pass<2>), dim3(64 * NCHUNK), dim3(256), 0, stream,
                       tb, Mr, sv, Psum, nullptr);
    hipMemsetAsync(out, 0, sizeof(float), stream);
    hipLaunchKernelGGL(fin_kernel, dim3(NROWS / 256), dim3(256), 0, stream,
                       Psum, Mr, num, out);
}